// Round 3
// baseline (311.412 us; speedup 1.0000x reference)
//
#include <hip/hip_runtime.h>
#include <stdint.h>

#define NBATCH 2
#define LL 4096
#define CC 256
#define LSTR8 144      // fp8 LDS row stride (bytes): 128+16 -> b64 frag reads 2-way/free
#define KEXP 0.09016844f   // (1/16) * log2(e)  : exp(acc/16) = exp2(acc*KEXP)
#define KEXP2 0.18033688f  // (2/16) * log2(e)
#define IMIN (-2147483647 - 1)
#define NBLK 1024          // fused grid: 4 blk/CU x 256 CU -> all resident

typedef long i64f;
typedef float f32x4 __attribute__((ext_vector_type(4)));

#if defined(__has_builtin) && __has_builtin(__builtin_amdgcn_exp2f)
#define EXP2F(x) __builtin_amdgcn_exp2f(x)
#else
#define EXP2F(x) exp2f(x)
#endif

// ---------------- prep: fp32 -> fp8 e4m3 cast + accumulator/barrier init ----
__global__ __launch_bounds__(256) void prep(
    const float* __restrict__ a, const float* __restrict__ b,
    uint32_t* __restrict__ oa, uint32_t* __restrict__ ob,
    float* __restrict__ rowSum, float* __restrict__ colSum,
    int* __restrict__ rowPart, int* __restrict__ colPart,
    int* __restrict__ barCtr){
  int gid = blockIdx.x * 256 + threadIdx.x;   // 262144 threads
  if (gid < NBATCH*LL){
    rowSum[gid] = 0.f; colSum[gid] = 0.f;
    rowPart[gid] = IMIN; colPart[gid] = IMIN;
  }
  if (gid == 0) *barCtr = 0;
  #pragma unroll
  for (int k = 0; k < 2; k++){
    int idx = gid*2 + k;                      // 524288 float4s per input
    float4 va = ((const float4*)a)[idx];
    float4 vb = ((const float4*)b)[idx];
    int ra = __builtin_amdgcn_cvt_pk_fp8_f32(va.x, va.y, 0, false);
    ra = __builtin_amdgcn_cvt_pk_fp8_f32(va.z, va.w, ra, true);
    int rb = __builtin_amdgcn_cvt_pk_fp8_f32(vb.x, vb.y, 0, false);
    rb = __builtin_amdgcn_cvt_pk_fp8_f32(vb.z, vb.w, rb, true);
    oa[idx] = (uint32_t)ra;
    ob[idx] = (uint32_t)rb;
  }
}

// ---------------- resident-grid software barrier ----------------------------
__device__ __forceinline__ void grid_barrier(int* ctr){
  __syncthreads();
  if (threadIdx.x == 0){
    __threadfence();   // drain our stores/atomics to the coherent point
    __hip_atomic_fetch_add(ctr, 1, __ATOMIC_RELEASE, __HIP_MEMORY_SCOPE_AGENT);
    while (__hip_atomic_load(ctr, __ATOMIC_ACQUIRE, __HIP_MEMORY_SCOPE_AGENT) < NBLK)
      __builtin_amdgcn_s_sleep(2);
  }
  __syncthreads();
}

// ---------------- on-the-fly fea for the rare mask hit ----------------------
__device__ float fea_fly(const float* __restrict__ featn, int srow, int t,
                         float* __restrict__ sred /*[9][4]*/, float* __restrict__ ssem /*[9]*/){
  int lane = t & 63, wv = t >> 6;
  int h = srow >> 6, xx = srow & 63;
  float fv = featn[(size_t)srow * CC + t];
  float uv[9];
  #pragma unroll
  for (int w = 0; w < 9; w++){
    int dy = w/3 - 1, dx = w%3 - 1;
    int y = h + dy, x = xx + dx;
    uv[w] = (y >= 0 && y < 64 && x >= 0 && x < 64) ? featn[(size_t)t * 4096 + y*64 + x] : 0.f;
  }
  __syncthreads();
  #pragma unroll
  for (int w = 0; w < 9; w++){
    float pvv = fv * uv[w];
    #pragma unroll
    for (int msk = 1; msk <= 32; msk <<= 1) pvv += __shfl_xor(pvv, msk);
    if (lane == 0) sred[w*4 + wv] = pvv;
  }
  __syncthreads();
  if (t < 9) ssem[t] = (sred[t*4+0] + sred[t*4+1] + sred[t*4+2] + sred[t*4+3]) * (1.f/256.f);
  __syncthreads();
  float acc = 0.f;
  #pragma unroll
  for (int w = 0; w < 9; w++) acc += uv[w] * ssem[w];
  __syncthreads();
  return acc;
}

__device__ __forceinline__ float pool_window(const float* f, const float* s, int t){
  if (t < 160){
    int a = (t*8)/5, e = (t*8+12)/5;
    float sum = 0.f;
    for (int i = a; i < e; i++) sum += f[i];
    return sum / (float)(e - a);
  } else {
    int tt = t - 160;
    int a = (tt*8)/3, e = (tt*8+10)/3;
    float sum = 0.f;
    for (int i = a; i < e; i++) sum += s[i];
    return sum / (float)(e - a);
  }
}

// ---------------- fused: conf (2 tiles/block) -> grid barrier -> tail (8 rows)
// All 1024 blocks co-resident: launch_bounds(256,4) caps VGPR at 128, LDS
// 36.9 KB -> 4 blk/CU exactly. Removes 2 kernel-dispatch ramps + gaps.
// C/D layout [m89]: l = lq*64+r*16+quad*4+rr, s = sq*64+j*16+lr
__global__ __launch_bounds__(256, 4) void fused(
    const uint8_t* __restrict__ f0q, const uint8_t* __restrict__ f1q,
    const float* __restrict__ feat0, const float* __restrict__ feat1,
    float* __restrict__ rowSum, float* __restrict__ colSum,
    int* __restrict__ rowPart, int* __restrict__ colPart,
    const float* __restrict__ lnw, const float* __restrict__ lnb,
    float* __restrict__ out, int* __restrict__ barCtr){
  __shared__ __align__(16) uint8_t smem[36864];
  uint8_t* Alds = smem;
  uint8_t* Blds = smem + 18432;
  int bl = blockIdx.x;
  int t = threadIdx.x;
  const int wv = t >> 6, lane = t & 63, lr = lane & 15, quad = lane >> 4;
  const int lq = wv >> 1, sq = wv & 1;

  // ======================= conf phase: 2 tiles =======================
  // XCD-chunked swizzle over 1024 blocks (1024 % 8 == 0 -> bijective);
  // the 2 tiles of one block share lt (A-panel L2-hot).
  int nbb = (bl & 7)*128 + (bl >> 3);
  for (int i = 0; i < 2; i++){
    int nb = nbb*2 + i;
    int st = nb & 31, lt = (nb >> 5) & 31, n = nb >> 10;
    const uint8_t* A = f0q + (size_t)n*LL*CC + (size_t)(lt*128)*CC;
    const uint8_t* B = f1q + (size_t)n*LL*CC + (size_t)(st*128)*CC;
    f32x4 acc[4][4];
    #pragma unroll
    for (int r = 0; r < 4; r++)
      #pragma unroll
      for (int j = 0; j < 4; j++) acc[r][j] = (f32x4){0.f,0.f,0.f,0.f};
    for (int kc = 0; kc < 2; kc++){
      __syncthreads();   // protect LDS from prior reads (epilogue/compute)
      #pragma unroll
      for (int m = 0; m < 8; m++){
        int f = m*256 + t, row = f >> 4, kg = f & 15;   // 8B chunks, 16/row
        *(uint2*)(Alds + row*LSTR8 + kg*8) =
            *(const uint2*)(A + (size_t)row*CC + kc*128 + kg*8);
        *(uint2*)(Blds + row*LSTR8 + kg*8) =
            *(const uint2*)(B + (size_t)row*CC + kc*128 + kg*8);
      }
      __syncthreads();
      #pragma unroll
      for (int kk = 0; kk < 4; kk++){
        i64f a[4], bf[4];
        #pragma unroll
        for (int r = 0; r < 4; r++)
          a[r] = *(const i64f*)(Alds + (lq*64 + r*16 + lr)*LSTR8 + kk*32 + quad*8);
        #pragma unroll
        for (int j = 0; j < 4; j++)
          bf[j] = *(const i64f*)(Blds + (sq*64 + j*16 + lr)*LSTR8 + kk*32 + quad*8);
        #pragma unroll
        for (int r = 0; r < 4; r++)
          #pragma unroll
          for (int j = 0; j < 4; j++)
            acc[r][j] = __builtin_amdgcn_mfma_f32_16x16x32_fp8_fp8(a[r], bf[j], acc[r][j], 0, 0, 0);
      }
    }
    // ---- epilogue: exp-sums + packed argmax keys ----
    const int sbase = st*128 + sq*64 + lr;        // + j*16
    const int lbase = lt*128 + lq*64 + quad*4;    // + r*16 + rr
    float rsum[4][4], csum[4] = {0.f,0.f,0.f,0.f};
    int rkey[4][4], ckey[4] = {IMIN,IMIN,IMIN,IMIN};
    #pragma unroll
    for (int r = 0; r < 4; r++)
      #pragma unroll
      for (int rr = 0; rr < 4; rr++){ rsum[r][rr] = 0.f; rkey[r][rr] = IMIN; }
    #pragma unroll
    for (int r = 0; r < 4; r++)
      #pragma unroll
      for (int j = 0; j < 4; j++)
        #pragma unroll
        for (int rr = 0; rr < 4; rr++){
          float a = acc[r][j][rr];
          float e = EXP2F(a * KEXP);
          rsum[r][rr] += e;
          csum[j] += e;
          int iqs = ((int)(a * 2048.f)) << 12;
          rkey[r][rr] = max(rkey[r][rr], iqs + (sbase + j*16));
          ckey[j]     = max(ckey[j],     iqs + (lbase + r*16 + rr));
        }
    #pragma unroll
    for (int msk = 1; msk <= 8; msk <<= 1)
      #pragma unroll
      for (int r = 0; r < 4; r++)
        #pragma unroll
        for (int rr = 0; rr < 4; rr++){
          rsum[r][rr] += __shfl_xor(rsum[r][rr], msk);
          rkey[r][rr] = max(rkey[r][rr], __shfl_xor(rkey[r][rr], msk));
        }
    #pragma unroll
    for (int msk = 16; msk <= 32; msk <<= 1)
      #pragma unroll
      for (int j = 0; j < 4; j++){
        csum[j] += __shfl_xor(csum[j], msk);
        ckey[j] = max(ckey[j], __shfl_xor(ckey[j], msk));
      }
    __syncthreads();   // all waves done reading tile LDS -> overlay is safe
    float* rowS = (float*)smem;            // [2][128] overlay
    float* colS = (float*)(smem + 1024);   // [2][128]
    int*   rb   = (int*)  (smem + 2048);   // [2][128]
    int*   cb   = (int*)  (smem + 3072);   // [2][128]
    if (lr == 0){
      #pragma unroll
      for (int r = 0; r < 4; r++)
        #pragma unroll
        for (int rr = 0; rr < 4; rr++){
          int row = lq*64 + r*16 + quad*4 + rr;
          rowS[sq*128 + row] = rsum[r][rr];   // single writer per slot
          rb[sq*128 + row]   = rkey[r][rr];
        }
    }
    if (quad == 0){
      #pragma unroll
      for (int j = 0; j < 4; j++){
        int col = sq*64 + j*16 + lr;
        colS[lq*128 + col] = csum[j];
        cb[lq*128 + col]   = ckey[j];
      }
    }
    __syncthreads();
    if (t < 128){
      unsafeAtomicAdd(&rowSum[(size_t)n*LL + lt*128 + t], rowS[t] + rowS[128 + t]);
      unsafeAtomicAdd(&colSum[(size_t)n*LL + st*128 + t], colS[t] + colS[128 + t]);
      atomicMax(&rowPart[(size_t)n*LL + lt*128 + t], max(rb[t], rb[128 + t]));
      atomicMax(&colPart[(size_t)n*LL + st*128 + t], max(cb[t], cb[128 + t]));
    }
  }

  // ======================= grid barrier =======================
  grid_barrier(barCtr);

  // ======================= tail phase: 8 rows =======================
  float* f0r  = (float*)smem;            // [256]
  float* f1r  = (float*)(smem + 1024);
  float* s0r  = (float*)(smem + 2048);
  float* s1r  = (float*)(smem + 3072);
  float* sred = (float*)(smem + 4096);   // [9][4]
  float* ssem = (float*)(smem + 4352);   // [9]
  float* redA = (float*)(smem + 4608);   // [2][4]
  float* redB = (float*)(smem + 4640);   // [2][4]
  float w = lnw[t], bsh = lnb[t];
  for (int i = 0; i < 8; i++){
    int tid2 = bl*8 + i;
    int n = tid2 >> 12, l = tid2 & 4095;
    size_t base = (size_t)n * LL;
    // hoist the feat-row loads; overlap the scalar chain below
    float fv0 = feat0[(base + l)*CC + t];
    float fv1 = feat1[(base + l)*CC + t];
    // fully-reduced scalars (uniform; 2-deep dependent chain)
    int   rowK = rowPart[base + l], colK = colPart[base + l];
    float Rl   = rowSum[base + l],  Cl   = colSum[base + l];
    int ssr = rowK & 4095, ssc = colK & 4095;
    float Cssr = colSum[base + ssr], Rssc = rowSum[base + ssc];
    int   ck2  = colPart[base + ssr], rk2 = rowPart[base + ssc];
    float v0 = 0.f, v1 = 0.f;
    {
      float araw = (float)(rowK >> 12) * (1.f/2048.f);
      float val = exp2f(araw * KEXP2) / (Rl * Cssr);   // conf'(l,ssr)
      if (val > 0.2f && (ck2 & 4095) == l)
        v0 = fea_fly(feat1 + (size_t)n*LL*CC, ssr, t, sred, ssem) * (1.f/4096.f);
    }
    {
      float araw = (float)(colK >> 12) * (1.f/2048.f);
      float val = exp2f(araw * KEXP2) / (Cl * Rssc);   // conf'(ssc,l)
      if (val > 0.2f && (rk2 & 4095) == l)
        v1 = fea_fly(feat0 + (size_t)n*LL*CC, ssc, t, sred, ssem) * (1.f/4096.f);
    }
    // ---- pool + LN ----
    f0r[t] = fv0;
    f1r[t] = fv1;
    s0r[t] = v0;
    s1r[t] = v1;
    __syncthreads();
    float pA = pool_window(f0r, s0r, t);
    float pB = pool_window(f1r, s1r, t);
    float smA = pA, sqA = pA*pA, smB = pB, sqB = pB*pB;
    #pragma unroll
    for (int msk = 1; msk <= 32; msk <<= 1){
      smA += __shfl_xor(smA, msk);
      sqA += __shfl_xor(sqA, msk);
      smB += __shfl_xor(smB, msk);
      sqB += __shfl_xor(sqB, msk);
    }
    if (lane == 0){ redA[0*4+wv] = smA; redA[1*4+wv] = sqA; redB[0*4+wv] = smB; redB[1*4+wv] = sqB; }
    __syncthreads();
    float tsA = redA[0]+redA[1]+redA[2]+redA[3];
    float tqA = redA[4]+redA[5]+redA[6]+redA[7];
    float tsB = redB[0]+redB[1]+redB[2]+redB[3];
    float tqB = redB[4]+redB[5]+redB[6]+redB[7];
    float muA = tsA * (1.f/256.f), varA = tqA * (1.f/256.f) - muA*muA;
    float muB = tsB * (1.f/256.f), varB = tqB * (1.f/256.f) - muB*muB;
    out[((size_t)n*LL + l)*CC + t]       = (pA - muA) * rsqrtf(varA + 1e-5f) * w + bsh;
    out[((size_t)(2 + n)*LL + l)*CC + t] = (pB - muB) * rsqrtf(varB + 1e-5f) * w + bsh;
    __syncthreads();   // protect f0r..s1r before next iteration's writes
  }
}

extern "C" void kernel_launch(void* const* d_in, const int* in_sizes, int n_in,
                              void* d_out, int out_size, void* d_ws, size_t ws_size,
                              hipStream_t stream){
  const float* feat0 = (const float*)d_in[0];
  const float* feat1 = (const float*)d_in[1];
  const float* lnw   = (const float*)d_in[2];
  const float* lnb   = (const float*)d_in[3];
  float* out = (float*)d_out;
  char* ws = (char*)d_ws;
  const size_t MB = 1024 * 1024;
  uint8_t* f0q = (uint8_t*)(ws + 0);        // 2 MB fp8
  uint8_t* f1q = (uint8_t*)(ws + 2*MB);     // 2 MB fp8
  float* rowSum  = (float*)(ws + 4*MB);            // [2][4096] = 32 KB
  float* colSum  = (float*)(ws + 4*MB + 32*1024);  // 32 KB
  int*   rowPart = (int*)  (ws + 4*MB + 64*1024);  // 32 KB
  int*   colPart = (int*)  (ws + 4*MB + 96*1024);  // 32 KB
  int*   barCtr  = (int*)  (ws + 4*MB + 128*1024); // 4 B

  prep<<<1024, 256, 0, stream>>>(feat0, feat1, (uint32_t*)f0q, (uint32_t*)f1q,
                                 rowSum, colSum, rowPart, colPart, barCtr);
  fused<<<NBLK, 256, 0, stream>>>(f0q, f1q, feat0, feat1,
                                  rowSum, colSum, rowPart, colPart,
                                  lnw, lnb, out, barCtr);
}

// Round 4
// 122.536 us; speedup vs baseline: 2.5414x; 2.5414x over previous
//
#include <hip/hip_runtime.h>
#include <stdint.h>

#define NBATCH 2
#define LL 4096
#define CC 256
#define KEXP 0.09016844f   // (1/16) * log2(e)  : exp(acc/16) = exp2(acc*KEXP)
#define KEXP2 0.18033688f  // (2/16) * log2(e)
#define IMIN (-2147483647 - 1)

typedef long i64f;
typedef float f32x4 __attribute__((ext_vector_type(4)));

#if defined(__has_builtin) && __has_builtin(__builtin_amdgcn_exp2f)
#define EXP2F(x) __builtin_amdgcn_exp2f(x)
#else
#define EXP2F(x) exp2f(x)
#endif

// async 16B global -> LDS (dest = wave-uniform base + lane*16)
#define GLDS16(g, l) __builtin_amdgcn_global_load_lds(                      \
    (const __attribute__((address_space(1))) uint32_t*)(g),                 \
    (__attribute__((address_space(3))) uint32_t*)(l), 16, 0, 0)

// ---------------- cast fp32 -> fp8 e4m3 (OCP, HW packer) + accum init -------
__global__ __launch_bounds__(256) void cast_fp8(
    const float* __restrict__ a, const float* __restrict__ b,
    uint32_t* __restrict__ oa, uint32_t* __restrict__ ob,
    float* __restrict__ rowSum, float* __restrict__ colSum,
    int* __restrict__ rowPart, int* __restrict__ colPart){
  int idx = blockIdx.x * 256 + threadIdx.x;   // one uint32 = 4 fp8 per thread
  if (idx < NBATCH*LL){
    rowSum[idx] = 0.f; colSum[idx] = 0.f;
    rowPart[idx] = IMIN; colPart[idx] = IMIN;
  }
  float4 va = ((const float4*)a)[idx];
  float4 vb = ((const float4*)b)[idx];
  int ra = __builtin_amdgcn_cvt_pk_fp8_f32(va.x, va.y, 0, false);
  ra = __builtin_amdgcn_cvt_pk_fp8_f32(va.z, va.w, ra, true);
  int rb = __builtin_amdgcn_cvt_pk_fp8_f32(vb.x, vb.y, 0, false);
  rb = __builtin_amdgcn_cvt_pk_fp8_f32(vb.z, vb.w, rb, true);
  oa[idx] = (uint32_t)ra;
  ob[idx] = (uint32_t)rb;
}

// ---------------- single conf pass: fp8 128x128, 2 K-chunks ----------------
// R14: linear 128B LDS rows + XOR swizzle (off ^= (row&7)<<4) on BOTH sides
// (pre-swizzled global source, swizzled frag reads) -> enables
// global_load_lds width=16 for chunk-0 staging (no reg round-trip, no
// ds_writes). Chunk-1 keeps the R11-verified register prefetch.
// C/D layout [m89]: l = lq*64+r*16+quad*4+rr, s = sq*64+j*16+lr
__global__ __launch_bounds__(256, 4) void conf_pass(
    const uint8_t* __restrict__ f0q, const uint8_t* __restrict__ f1q,
    float* __restrict__ rowSum, float* __restrict__ colSum,
    int* __restrict__ rowPart, int* __restrict__ colPart){
  __shared__ __align__(16) uint8_t Alds[128*128];
  __shared__ __align__(16) uint8_t Blds[128*128];
  float* rowS = (float*)Alds;            // [2][128] overlay (valid after MFMA)
  float* colS = (float*)(Alds + 1024);   // [2][128]
  int*   rb   = (int*)  (Alds + 2048);   // [2][128]
  int*   cb   = (int*)  (Alds + 3072);   // [2][128]
  // XCD-chunked swizzle: 2048 blocks, 8 XCDs, 256 contiguous tiles per XCD.
  int bl = (blockIdx.z*32 + blockIdx.y)*32 + blockIdx.x;
  int nb = (bl & 7)*256 + (bl >> 3);
  int st = nb & 31, lt = (nb >> 5) & 31, n = nb >> 10;
  int t = threadIdx.x;
  const int wv = t >> 6, lane = t & 63, lr = lane & 15, quad = lane >> 4;
  const int lq = wv >> 1, sq = wv & 1;
  const int swzr = (lr & 7) << 4;        // frag-read XOR (row&7 == lr&7)
  const uint8_t* A = f0q + (size_t)n*LL*CC + (size_t)(lt*128)*CC;
  const uint8_t* B = f1q + (size_t)n*LL*CC + (size_t)(st*128)*CC;
  f32x4 acc[4][4];
  #pragma unroll
  for (int r = 0; r < 4; r++)
    #pragma unroll
    for (int j = 0; j < 4; j++) acc[r][j] = (f32x4){0.f,0.f,0.f,0.f};

  auto compute = [&](){
    #pragma unroll
    for (int kk = 0; kk < 4; kk++){
      int off = (kk*32 + quad*8) ^ swzr;
      i64f a[4], bf[4];
      #pragma unroll
      for (int r = 0; r < 4; r++)
        a[r] = *(const i64f*)(Alds + (lq*64 + r*16 + lr)*128 + off);
      #pragma unroll
      for (int j = 0; j < 4; j++)
        bf[j] = *(const i64f*)(Blds + (sq*64 + j*16 + lr)*128 + off);
      #pragma unroll
      for (int r = 0; r < 4; r++)
        #pragma unroll
        for (int j = 0; j < 4; j++)
          acc[r][j] = __builtin_amdgcn_mfma_f32_16x16x32_fp8_fp8(a[r], bf[j], acc[r][j], 0, 0, 0);
    }
  };

  // ---- chunk 0: async global_load_lds, 16B/lane, pre-swizzled source ----
  // LDS linear offset o = m*4096 + wv*1024 + lane*16 -> row = o>>7 = m*32+wv*8+(lane>>3),
  // lds_off = (lane&7)*16; source byte = row*256 + (lds_off ^ ((row&7)<<4)).
  {
    int rsub = lane >> 3, csub = lane & 7;
    int srcOff = ((csub ^ rsub) << 4);           // row&7 == rsub here
    #pragma unroll
    for (int m = 0; m < 4; m++){
      int row = m*32 + wv*8 + rsub;
      GLDS16(A + (size_t)row*CC + srcOff, Alds + m*4096 + wv*1024);
      GLDS16(B + (size_t)row*CC + srcOff, Blds + m*4096 + wv*1024);
    }
  }
  // ---- chunk-1 prefetch into registers (in flight across compute 0) ----
  // lds[row][kg*8] will hold g[row][(kg*8) ^ ((row&7)<<4)] -> load swizzled src.
  uint2 pa[8], pb[8];
  #pragma unroll
  for (int m = 0; m < 8; m++){
    int f = m*256 + t, row = f >> 4, kg = f & 15;
    int so = (kg*8) ^ ((row & 7) << 4);
    pa[m] = *(const uint2*)(A + (size_t)row*CC + 128 + so);
    pb[m] = *(const uint2*)(B + (size_t)row*CC + 128 + so);
  }
  __syncthreads();    // vmcnt(0) drain: glds chunk-0 + prefetch complete
  compute();          // chunk 0
  __syncthreads();
  #pragma unroll
  for (int m = 0; m < 8; m++){
    int f = m*256 + t, row = f >> 4, kg = f & 15;
    *(uint2*)(Alds + row*128 + kg*8) = pa[m];
    *(uint2*)(Blds + row*128 + kg*8) = pb[m];
  }
  __syncthreads();
  compute();          // chunk 1

  // ---- epilogue: exp-sums + packed argmax keys (registers + shuffles) ----
  const int sbase = st*128 + sq*64 + lr;        // + j*16
  const int lbase = lt*128 + lq*64 + quad*4;    // + r*16 + rr
  float rsum[4][4], csum[4] = {0.f,0.f,0.f,0.f};
  int rkey[4][4], ckey[4] = {IMIN,IMIN,IMIN,IMIN};
  #pragma unroll
  for (int r = 0; r < 4; r++)
    #pragma unroll
    for (int rr = 0; rr < 4; rr++){ rsum[r][rr] = 0.f; rkey[r][rr] = IMIN; }
  #pragma unroll
  for (int r = 0; r < 4; r++)
    #pragma unroll
    for (int j = 0; j < 4; j++)
      #pragma unroll
      for (int rr = 0; rr < 4; rr++){
        float a = acc[r][j][rr];
        float e = EXP2F(a * KEXP);
        rsum[r][rr] += e;
        csum[j] += e;
        int iqs = ((int)(a * 2048.f)) << 12;
        rkey[r][rr] = max(rkey[r][rr], iqs + (sbase + j*16));
        ckey[j]     = max(ckey[j],     iqs + (lbase + r*16 + rr));
      }
  #pragma unroll
  for (int msk = 1; msk <= 8; msk <<= 1)
    #pragma unroll
    for (int r = 0; r < 4; r++)
      #pragma unroll
      for (int rr = 0; rr < 4; rr++){
        rsum[r][rr] += __shfl_xor(rsum[r][rr], msk);
        rkey[r][rr] = max(rkey[r][rr], __shfl_xor(rkey[r][rr], msk));
      }
  #pragma unroll
  for (int msk = 16; msk <= 32; msk <<= 1)
    #pragma unroll
    for (int j = 0; j < 4; j++){
      csum[j] += __shfl_xor(csum[j], msk);
      ckey[j] = max(ckey[j], __shfl_xor(ckey[j], msk));
    }
  __syncthreads();   // all waves done reading tile LDS -> overlay is safe
  if (lr == 0){
    #pragma unroll
    for (int r = 0; r < 4; r++)
      #pragma unroll
      for (int rr = 0; rr < 4; rr++){
        int row = lq*64 + r*16 + quad*4 + rr;
        rowS[sq*128 + row] = rsum[r][rr];   // single writer per slot
        rb[sq*128 + row]   = rkey[r][rr];
      }
  }
  if (quad == 0){
    #pragma unroll
    for (int j = 0; j < 4; j++){
      int col = sq*64 + j*16 + lr;
      colS[lq*128 + col] = csum[j];
      cb[lq*128 + col]   = ckey[j];
    }
  }
  __syncthreads();
  if (t < 128){
    unsafeAtomicAdd(&rowSum[(size_t)n*LL + lt*128 + t], rowS[t] + rowS[128 + t]);
    unsafeAtomicAdd(&colSum[(size_t)n*LL + st*128 + t], colS[t] + colS[128 + t]);
    atomicMax(&rowPart[(size_t)n*LL + lt*128 + t], max(rb[t], rb[128 + t]));
    atomicMax(&colPart[(size_t)n*LL + st*128 + t], max(cb[t], cb[128 + t]));
  }
}

// ---------------- on-the-fly fea for the rare mask hit ----------------
__device__ float fea_fly(const float* __restrict__ featn, int srow, int t){
  __shared__ float sred[9][4];
  __shared__ float ssem[9];
  int lane = t & 63, wv = t >> 6;
  int h = srow >> 6, xx = srow & 63;
  float fv = featn[(size_t)srow * CC + t];
  float uv[9];
  #pragma unroll
  for (int w = 0; w < 9; w++){
    int dy = w/3 - 1, dx = w%3 - 1;
    int y = h + dy, x = xx + dx;
    uv[w] = (y >= 0 && y < 64 && x >= 0 && x < 64) ? featn[(size_t)t * 4096 + y*64 + x] : 0.f;
  }
  __syncthreads();
  #pragma unroll
  for (int w = 0; w < 9; w++){
    float pvv = fv * uv[w];
    #pragma unroll
    for (int msk = 1; msk <= 32; msk <<= 1) pvv += __shfl_xor(pvv, msk);
    if (lane == 0) sred[w][wv] = pvv;
  }
  __syncthreads();
  if (t < 9) ssem[t] = (sred[t][0] + sred[t][1] + sred[t][2] + sred[t][3]) * (1.f/256.f);
  __syncthreads();
  float acc = 0.f;
  #pragma unroll
  for (int w = 0; w < 9; w++) acc += uv[w] * ssem[w];
  __syncthreads();
  return acc;
}

__device__ __forceinline__ float pool_window(const float* f, const float* s, int t){
  if (t < 160){
    int a = (t*8)/5, e = (t*8+12)/5;
    float sum = 0.f;
    for (int i = a; i < e; i++) sum += f[i];
    return sum / (float)(e - a);
  } else {
    int tt = t - 160;
    int a = (tt*8)/3, e = (tt*8+10)/3;
    float sum = 0.f;
    for (int i = a; i < e; i++) sum += s[i];
    return sum / (float)(e - a);
  }
}

// ---------------- fused tail: mutual-NN check + pool + LN -------------------
__global__ __launch_bounds__(256) void tail(
    const float* __restrict__ feat0, const float* __restrict__ feat1,
    const float* __restrict__ rowSum, const float* __restrict__ colSum,
    const int* __restrict__ rowPart, const int* __restrict__ colPart,
    const float* __restrict__ lnw, const float* __restrict__ lnb,
    float* __restrict__ out){
  int l = blockIdx.x, n = blockIdx.y, t = threadIdx.x;
  int lane = t & 63, wv = t >> 6;
  size_t base = (size_t)n * LL;
  // hoist: issue the feat-row + LN loads NOW so their HBM latency overlaps
  // the dependent scalar-gather chain below.
  float fv0 = feat0[(base + l)*CC + t];
  float fv1 = feat1[(base + l)*CC + t];
  float w = lnw[t], bsh = lnb[t];
  // ---- fully-reduced scalars (uniform; dependent chain of 2 loads) ----
  int   rowK = rowPart[base + l], colK = colPart[base + l];
  float Rl   = rowSum[base + l],  Cl   = colSum[base + l];
  int ssr = rowK & 4095, ssc = colK & 4095;
  float Cssr = colSum[base + ssr], Rssc = rowSum[base + ssc];
  int   ck2  = colPart[base + ssr], rk2 = rowPart[base + ssc];
  float v0 = 0.f, v1 = 0.f;
  {
    float araw = (float)(rowK >> 12) * (1.f/2048.f);
    float val = exp2f(araw * KEXP2) / (Rl * Cssr);   // conf'(l,ssr)
    if (val > 0.2f && (ck2 & 4095) == l)
      v0 = fea_fly(feat1 + (size_t)n*LL*CC, ssr, t) * (1.f/4096.f);
  }
  {
    float araw = (float)(colK >> 12) * (1.f/2048.f);
    float val = exp2f(araw * KEXP2) / (Cl * Rssc);   // conf'(ssc,l)
    if (val > 0.2f && (rk2 & 4095) == l)
      v1 = fea_fly(feat0 + (size_t)n*LL*CC, ssc, t) * (1.f/4096.f);
  }
  // ---- pool + LN ----
  __shared__ float f0r[CC], f1r[CC], s0r[CC], s1r[CC];
  __shared__ float redA[2][4], redB[2][4];
  f0r[t] = fv0;
  f1r[t] = fv1;
  s0r[t] = v0;
  s1r[t] = v1;
  __syncthreads();
  float pA = pool_window(f0r, s0r, t);
  float pB = pool_window(f1r, s1r, t);
  float smA = pA, sqA = pA*pA, smB = pB, sqB = pB*pB;
  #pragma unroll
  for (int msk = 1; msk <= 32; msk <<= 1){
    smA += __shfl_xor(smA, msk);
    sqA += __shfl_xor(sqA, msk);
    smB += __shfl_xor(smB, msk);
    sqB += __shfl_xor(sqB, msk);
  }
  if (lane == 0){ redA[0][wv] = smA; redA[1][wv] = sqA; redB[0][wv] = smB; redB[1][wv] = sqB; }
  __syncthreads();
  float tsA = redA[0][0]+redA[0][1]+redA[0][2]+redA[0][3];
  float tqA = redA[1][0]+redA[1][1]+redA[1][2]+redA[1][3];
  float tsB = redB[0][0]+redB[0][1]+redB[0][2]+redB[0][3];
  float tqB = redB[1][0]+redB[1][1]+redB[1][2]+redB[1][3];
  float muA = tsA * (1.f/256.f), varA = tqA * (1.f/256.f) - muA*muA;
  float muB = tsB * (1.f/256.f), varB = tqB * (1.f/256.f) - muB*muB;
  out[((size_t)n*LL + l)*CC + t]       = (pA - muA) * rsqrtf(varA + 1e-5f) * w + bsh;
  out[((size_t)(2 + n)*LL + l)*CC + t] = (pB - muB) * rsqrtf(varB + 1e-5f) * w + bsh;
}

extern "C" void kernel_launch(void* const* d_in, const int* in_sizes, int n_in,
                              void* d_out, int out_size, void* d_ws, size_t ws_size,
                              hipStream_t stream){
  const float* feat0 = (const float*)d_in[0];
  const float* feat1 = (const float*)d_in[1];
  const float* lnw   = (const float*)d_in[2];
  const float* lnb   = (const float*)d_in[3];
  float* out = (float*)d_out;
  char* ws = (char*)d_ws;
  const size_t MB = 1024 * 1024;
  uint8_t* f0q = (uint8_t*)(ws + 0);        // 2 MB fp8
  uint8_t* f1q = (uint8_t*)(ws + 2*MB);     // 2 MB fp8
  float* rowSum  = (float*)(ws + 4*MB);            // [2][4096] = 32 KB
  float* colSum  = (float*)(ws + 4*MB + 32*1024);  // 32 KB
  int*   rowPart = (int*)  (ws + 4*MB + 64*1024);  // 32 KB
  int*   colPart = (int*)  (ws + 4*MB + 96*1024);  // 32 KB

  cast_fp8<<<2048, 256, 0, stream>>>(feat0, feat1, (uint32_t*)f0q, (uint32_t*)f1q,
                                     rowSum, colSum, rowPart, colPart);
  dim3 gconf(32, 32, NBATCH);
  conf_pass<<<gconf, 256, 0, stream>>>(f0q, f1q, rowSum, colSum, rowPart, colPart);
  dim3 gt(LL, NBATCH);
  tail<<<gt, 256, 0, stream>>>(feat0, feat1, rowSum, colSum, rowPart, colPart,
                               lnw, lnb, out);
}